// Round 4
// baseline (518.982 us; speedup 1.0000x reference)
//
#include <hip/hip_runtime.h>
#include <math.h>

#define TNUM 8192
#define BNUM 8
#define DV 1024
#define DQ 768
#define KREP 6
#define NHEAD 8
#define HD 128
#define CANDN 18
#define APAD 132   // LDS row stride for attn head tiles (132%32=4 -> no stride-128 bank conflict)

// ---------------- helpers ----------------
__device__ __forceinline__ double wave_reduce_sum(double v) {
    for (int off = 32; off > 0; off >>= 1) v += __shfl_down(v, off);
    return v;
}
__device__ __forceinline__ float wave_reduce_sumf(float v) {
    for (int off = 32; off > 0; off >>= 1) v += __shfl_down(v, off);
    return v;
}

// ---------------- K1: h = x @ w1.T + b1 (both branches, f64) ----------------
__global__ void k_mlp1(const float* __restrict__ q,
                       const float* __restrict__ mu_w1, const float* __restrict__ mu_b1,
                       const float* __restrict__ sg_w1, const float* __restrict__ sg_b1,
                       double* __restrict__ h) {
    int o = blockIdx.x, b = blockIdx.y, br = blockIdx.z;
    const float* w  = br ? sg_w1 : mu_w1;
    const float* bb = br ? sg_b1 : mu_b1;
    const float* x  = q + (size_t)b * DQ;
    const float* wr = w + (size_t)o * DQ;
    double acc = 0.0;
    for (int j = threadIdx.x; j < DQ; j += 64)
        acc += (double)x[j] * (double)wr[j];
    acc = wave_reduce_sum(acc);
    if (threadIdx.x == 0)
        h[((size_t)br * BNUM + b) * DV + o] = acc + (double)bb[o];
}

// ---------------- K2: LayerNorm + ReLU in-place (f64) ----------------
__global__ void k_ln(double* __restrict__ h,
                     const float* __restrict__ mg, const float* __restrict__ mbt,
                     const float* __restrict__ sg, const float* __restrict__ sbt) {
    int b = blockIdx.x, br = blockIdx.y;
    const float* g  = br ? sg  : mg;
    const float* bt = br ? sbt : mbt;
    double* row = h + ((size_t)br * BNUM + b) * DV;
    __shared__ double sc[4];
    __shared__ double s_mean, s_rstd;
    int tid = threadIdx.x, wid = tid >> 6, lane = tid & 63;

    double s = 0.0;
    for (int j = tid; j < DV; j += 256) s += row[j];
    s = wave_reduce_sum(s);
    if (lane == 0) sc[wid] = s;
    __syncthreads();
    if (tid == 0) s_mean = (sc[0] + sc[1] + sc[2] + sc[3]) / (double)DV;
    __syncthreads();
    double mean = s_mean;

    double v = 0.0;
    for (int j = tid; j < DV; j += 256) { double c = row[j] - mean; v += c * c; }
    v = wave_reduce_sum(v);
    if (lane == 0) sc[wid] = v;
    __syncthreads();
    if (tid == 0) s_rstd = 1.0 / sqrt((sc[0] + sc[1] + sc[2] + sc[3]) / (double)DV + 1e-5);
    __syncthreads();
    double rstd = s_rstd;

    for (int j = tid; j < DV; j += 256) {
        double val = (row[j] - mean) * rstd * (double)g[j] + (double)bt[j];
        row[j] = val > 0.0 ? val : 0.0;
    }
}

// ---------------- K3: out = h2 @ w2.T + b2; mu / softplus-sigma (f64) ----------------
__global__ void k_mlp2(const double* __restrict__ h,
                       const float* __restrict__ mu_w2, const float* __restrict__ mu_b2,
                       const float* __restrict__ sg_w2, const float* __restrict__ sg_b2,
                       double* __restrict__ mu, double* __restrict__ rsig,
                       float* __restrict__ out_mu, float* __restrict__ out_sg) {
    int o = blockIdx.x, b = blockIdx.y, br = blockIdx.z;
    const float* w  = br ? sg_w2 : mu_w2;
    const float* bb = br ? sg_b2 : mu_b2;
    const double* row = h + ((size_t)br * BNUM + b) * DV;
    const float* wr = w + (size_t)o * DV;
    double acc = 0.0;
    for (int j = threadIdx.x; j < DV; j += 64)
        acc += row[j] * (double)wr[j];
    acc = wave_reduce_sum(acc);
    if (threadIdx.x == 0) {
        double v = acc + (double)bb[o];
        if (br == 0) {
            mu[(size_t)b * DV + o] = v;
            out_mu[b * DV + o] = (float)v;
        } else {
            double sp = fmax(v, 0.0) + log1p(exp(-fabs(v)));  // stable softplus
            double sig = sp + 1e-6;
            rsig[(size_t)b * DV + o] = 1.0 / sig;
            out_sg[b * DV + o] = (float)sig;
        }
    }
}

// ---------------- K4: Mahalanobis dist; mu/rsig cached in registers, 32 rows/block ----------------
__global__ void __launch_bounds__(256) k_dist(
        const float* __restrict__ feat,
        const double* __restrict__ mu, const double* __restrict__ rsig,
        double* __restrict__ distw, float* __restrict__ dist_out) {
    int wid = threadIdx.x >> 6, lane = threadIdx.x & 63;
    int b = blockIdx.y;
    int t0 = blockIdx.x * 32;
    const double* m = mu   + (size_t)b * DV;
    const double* r = rsig + (size_t)b * DV;
    // per-lane register cache of the 32 mu/rsig entries this lane needs
    double md[4][4], rd[4][4];
#pragma unroll
    for (int qq = 0; qq < 4; ++qq) {
        int j = (lane + 64 * qq) * 4;
#pragma unroll
        for (int e = 0; e < 4; ++e) { md[qq][e] = m[j + e]; rd[qq][e] = r[j + e]; }
    }
#pragma unroll 2
    for (int rr = 0; rr < 8; ++rr) {
        int t = t0 + rr * 4 + wid;
        const float4* f4 = (const float4*)(feat + ((size_t)b * TNUM + t) * DV);
        double acc = 0.0;
#pragma unroll
        for (int qq = 0; qq < 4; ++qq) {
            float4 f = f4[lane + 64 * qq];
            double c0 = (double)f.x - md[qq][0];
            double c1 = (double)f.y - md[qq][1];
            double c2 = (double)f.z - md[qq][2];
            double c3 = (double)f.w - md[qq][3];
            acc += c0 * c0 * rd[qq][0] + c1 * c1 * rd[qq][1]
                 + c2 * c2 * rd[qq][2] + c3 * c3 * rd[qq][3];
        }
        acc = wave_reduce_sum(acc);
        if (lane == 0) {
            distw[(size_t)b * TNUM + t] = acc;
            dist_out[b * TNUM + t] = (float)acc;
        }
    }
}

// ---------------- K5: radix-select (normalized keys) + top-18 + diversify ----------------
struct SelShared {
    unsigned int hist[256];
    unsigned long long pref;
    int krem;
    unsigned long long kmn[16], kmx[16];
    unsigned long long s_kmin;
    int s_shift;
};

__device__ __forceinline__ unsigned long long raw_key(double v) {
    return (unsigned long long)__double_as_longlong(v);
}

__device__ void block_norm_params(const double* sw, int absmode, double med,
                                  SelShared* S, int tid) {
    unsigned long long mn = ~0ULL, mx = 0ULL;
    for (int i = tid; i < TNUM; i += 1024) {
        double v = sw[i];
        if (absmode) v = fabs(v - med);
        unsigned long long k = raw_key(v);
        mn = mn < k ? mn : k;
        mx = mx > k ? mx : k;
    }
    for (int off = 32; off > 0; off >>= 1) {
        unsigned long long omn = __shfl_down(mn, off);
        unsigned long long omx = __shfl_down(mx, off);
        mn = mn < omn ? mn : omn;
        mx = mx > omx ? mx : omx;
    }
    int lane = tid & 63, wid = tid >> 6;
    if (lane == 0) { S->kmn[wid] = mn; S->kmx[wid] = mx; }
    __syncthreads();
    if (tid == 0) {
        unsigned long long fmn = S->kmn[0], fmx = S->kmx[0];
        for (int k = 1; k < 16; ++k) {
            if (S->kmn[k] < fmn) fmn = S->kmn[k];
            if (S->kmx[k] > fmx) fmx = S->kmx[k];
        }
        unsigned long long diff = fmx - fmn;
        S->s_kmin = fmn;
        S->s_shift = diff ? __clzll((long long)diff) : 0;
    }
    __syncthreads();
}

__device__ __forceinline__ unsigned long long norm_key(double v, int absmode, double med,
                                                       unsigned long long kmin, int shift) {
    unsigned long long k = raw_key(absmode ? fabs(v - med) : v);
    return (k - kmin) << shift;
}

__device__ unsigned long long block_radix_select(
        const double* sw, int rank, int absmode, double med, SelShared* S, int tid) {
    unsigned long long kmin = S->s_kmin;
    int shift = S->s_shift;
    if (tid == 0) { S->pref = 0ULL; S->krem = rank; }
    __syncthreads();
    for (int p = 0; p < 8; ++p) {
        for (int cc = tid; cc < 256; cc += 1024) S->hist[cc] = 0;
        __syncthreads();
        unsigned long long pref = S->pref;
        int known = 8 * p;
        int sh = 56 - known;
        for (int i = tid; i < TNUM; i += 1024) {
            unsigned long long key = norm_key(sw[i], absmode, med, kmin, shift);
            bool ok = (known == 0) || ((key >> (64 - known)) == (pref >> (64 - known)));
            if (ok) atomicAdd(&S->hist[(unsigned)((key >> sh) & 255ULL)], 1u);
        }
        __syncthreads();
        if (tid < 64) {
            unsigned int s0 = S->hist[tid * 4] + S->hist[tid * 4 + 1] +
                              S->hist[tid * 4 + 2] + S->hist[tid * 4 + 3];
            unsigned int incl = s0;
            for (int off = 1; off < 64; off <<= 1) {
                unsigned int v = __shfl_up(incl, off);
                if (tid >= off) incl += v;
            }
            int krem = S->krem;
            unsigned long long msk = __ballot(incl > (unsigned int)krem);
            int fl = __ffsll((unsigned long long)msk) - 1;
            if (tid == fl) {
                int k = krem - (int)(incl - s0);
                int c = tid * 4;
                while (k >= (int)S->hist[c]) { k -= (int)S->hist[c]; ++c; }
                S->krem = k;
                S->pref = pref | ((unsigned long long)(unsigned)c << sh);
            }
        }
        __syncthreads();
    }
    return S->pref;
}

__global__ void __launch_bounds__(1024) k_select(
        const double* __restrict__ distw,
        float* __restrict__ idx_out, int* __restrict__ idx_int) {
    __shared__ double sw[TNUM];           // 64 KB
    __shared__ SelShared S;
    __shared__ int s_cntlt, s_cnteq, s_nlt;
    __shared__ int s_lt[32];
    __shared__ int s_eq[64];
    __shared__ int s_eqs[CANDN];
    __shared__ int s_cand[CANDN];
    int b = blockIdx.x, tid = threadIdx.x;
    const double* w = distw + (size_t)b * TNUM;
    for (int i = tid; i < TNUM; i += 1024) sw[i] = w[i];
    __syncthreads();

    // lower median: rank 4095 of 8192
    block_norm_params(sw, 0, 0.0, &S, tid);
    unsigned long long kmin1 = S.s_kmin; int shift1 = S.s_shift;
    unsigned long long mk = block_radix_select(sw, (TNUM - 1) / 2, 0, 0.0, &S, tid);
    double med = __longlong_as_double((long long)((mk >> shift1) + kmin1));
    __syncthreads();

    // 18th-smallest |d - med| (normalized key K)
    block_norm_params(sw, 1, med, &S, tid);
    unsigned long long kmin2 = S.s_kmin; int shift2 = S.s_shift;
    unsigned long long K = block_radix_select(sw, CANDN - 1, 1, med, &S, tid);

    if (tid == 0) { s_cntlt = 0; s_cnteq = 0; }
    __syncthreads();
    for (int i = tid; i < TNUM; i += 1024) {
        unsigned long long key = norm_key(sw[i], 1, med, kmin2, shift2);
        if (key < K) { int p = atomicAdd(&s_cntlt, 1); if (p < 32) s_lt[p] = i; }
        else if (key == K) { int p = atomicAdd(&s_cnteq, 1); if (p < 64) s_eq[p] = i; }
    }
    __syncthreads();

    // wave 0: sort eq-class by index, keep the (18 - nlt) smallest
    if (tid < 64) {
        int nlt = s_cntlt; if (nlt > CANDN - 1) nlt = CANDN - 1;
        int neq = s_cnteq; if (neq > 64) neq = 64;
        int need = CANDN - nlt;
        int mye = (tid < neq) ? s_eq[tid] : 0x7FFFFFFF;
        int r = 0;
        for (int j = 0; j < neq; ++j) { int oj = __shfl(mye, j); if (oj < mye) ++r; }
        if (tid < neq && r < need) s_eqs[r] = mye;
        if (tid == 0) s_nlt = nlt;
    }
    __syncthreads();

    // wave 0: rank-sort the 18 candidates by (key, idx) ascending = lax.top_k order
    if (tid < 64) {
        int nlt = s_nlt;
        unsigned long long mykey; int myidx;
        if (tid < nlt) {
            myidx = s_lt[tid];
            mykey = norm_key(sw[myidx], 1, med, kmin2, shift2);
        } else if (tid < CANDN) {
            myidx = s_eqs[tid - nlt];
            mykey = K;
        } else { myidx = 0x7FFFFFFF; mykey = ~0ULL; }
        int r = 0;
        for (int j = 0; j < CANDN; ++j) {
            unsigned long long kj = __shfl(mykey, j);
            int ij = __shfl(myidx, j);
            if (kj < mykey || (kj == mykey && ij < myidx)) ++r;
        }
        if (tid < CANDN) s_cand[r] = myidx;
    }
    __syncthreads();

    // wave 0: greedy farthest-point diversify (f32, argmax first-occurrence)
    if (tid < 64) {
        int ci = (tid < CANDN) ? s_cand[tid] : 0;
        float cf = (float)ci;
        float c0 = __shfl(cf, 0);
        const float NEG = -__builtin_huge_valf();
        float mind = (tid < CANDN) ? fabsf(cf - c0) : NEG;
        if (tid == 0) {
            mind = NEG;
            idx_out[b * KREP] = (float)ci;
            idx_int[b * KREP] = ci;
        }
        for (int s = 1; s < KREP; ++s) {
            float bv = mind; int bl = tid;
            for (int off = 32; off > 0; off >>= 1) {
                float ov = __shfl_down(bv, off);
                int   ol = __shfl_down(bl, off);
                if (ov > bv || (ov == bv && ol < bl)) { bv = ov; bl = ol; }
            }
            int bestlane = __shfl(bl, 0);
            float bf = __shfl(cf, bestlane);
            int   bi = __shfl(ci, bestlane);
            if (tid == 0) {
                idx_out[b * KREP + s] = (float)bi;
                idx_int[b * KREP + s] = bi;
            }
            mind = fminf(mind, fabsf(cf - bf));
            if (tid == bestlane) mind = NEG;
        }
    }
}

// ---------------- K6: qkv = rep @ in_w.T + in_b; 4 weight rows in regs per wave ----------------
__global__ void __launch_bounds__(256) k_qkv(
        const float* __restrict__ feat, const int* __restrict__ idxi,
        const float* __restrict__ in_w, const float* __restrict__ in_b,
        float* __restrict__ qkv) {
    int wid = threadIdx.x >> 6, lane = threadIdx.x & 63;
    int o0 = blockIdx.x * 4;
    const float4* w4 = (const float4*)in_w;
    float4 wr[4][4];
#pragma unroll
    for (int rr = 0; rr < 4; ++rr)
#pragma unroll
        for (int qq = 0; qq < 4; ++qq)
            wr[rr][qq] = w4[(size_t)(o0 + rr) * 256 + lane + 64 * qq];
#pragma unroll
    for (int tt = 0; tt < 12; ++tt) {
        int tok = wid + 4 * tt;
        int b = tok / KREP;
        int t = idxi[tok];
        const float4* f4 = (const float4*)(feat + ((size_t)b * TNUM + t) * DV);
        float4 fq[4];
#pragma unroll
        for (int qq = 0; qq < 4; ++qq) fq[qq] = f4[lane + 64 * qq];
        float a0 = 0.f, a1 = 0.f, a2 = 0.f, a3 = 0.f;
#pragma unroll
        for (int qq = 0; qq < 4; ++qq) {
            float4 f = fq[qq];
            a0 += f.x * wr[0][qq].x + f.y * wr[0][qq].y + f.z * wr[0][qq].z + f.w * wr[0][qq].w;
            a1 += f.x * wr[1][qq].x + f.y * wr[1][qq].y + f.z * wr[1][qq].z + f.w * wr[1][qq].w;
            a2 += f.x * wr[2][qq].x + f.y * wr[2][qq].y + f.z * wr[2][qq].z + f.w * wr[2][qq].w;
            a3 += f.x * wr[3][qq].x + f.y * wr[3][qq].y + f.z * wr[3][qq].z + f.w * wr[3][qq].w;
        }
        a0 = wave_reduce_sumf(a0);
        a1 = wave_reduce_sumf(a1);
        a2 = wave_reduce_sumf(a2);
        a3 = wave_reduce_sumf(a3);
        if (lane == 0) {
            float* dst = qkv + (size_t)tok * (3 * DV) + o0;
            dst[0] = a0 + in_b[o0];
            dst[1] = a1 + in_b[o0 + 1];
            dst[2] = a2 + in_b[o0 + 2];
            dst[3] = a3 + in_b[o0 + 3];
        }
    }
}

// ---------------- K7: fused attention + head-mean; one block per batch, one wave per head ----------------
__global__ void __launch_bounds__(512) k_attn(
        const float* __restrict__ qkv,
        float* __restrict__ ctx, float* __restrict__ out_attn) {
    int b = blockIdx.x;
    int tid = threadIdx.x, h = tid >> 6, lane = tid & 63;
    __shared__ float sq[NHEAD][KREP * APAD];
    __shared__ float sk[NHEAD][KREP * APAD];
    __shared__ float sv[NHEAD][KREP * APAD];
    __shared__ float sat[NHEAD][KREP * KREP];

    for (int p = lane; p < KREP * HD; p += 64) {
        int i = p >> 7, d = p & 127;
        size_t base = (size_t)(b * KREP + i) * (3 * DV) + h * HD + d;
        sq[h][i * APAD + d] = qkv[base];
        sk[h][i * APAD + d] = qkv[base + DV];
        sv[h][i * APAD + d] = qkv[base + 2 * DV];
    }
    __syncthreads();

    if (lane < KREP * KREP) {
        int i = lane / KREP, j = lane % KREP;
        float s = 0.0f;
        for (int d = 0; d < HD; ++d)
            s += sq[h][i * APAD + d] * sk[h][j * APAD + d];
        sat[h][lane] = s / sqrtf((float)HD);
    }
    __syncthreads();

    if (lane < KREP) {
        int i = lane;
        float m = sat[h][i * KREP];
        for (int j = 1; j < KREP; ++j) m = fmaxf(m, sat[h][i * KREP + j]);
        float sum = 0.0f;
        for (int j = 0; j < KREP; ++j) {
            float e = expf(sat[h][i * KREP + j] - m);
            sum += e; sat[h][i * KREP + j] = e;
        }
        float inv = 1.0f / sum;
        for (int j = 0; j < KREP; ++j) sat[h][i * KREP + j] *= inv;
    }
    __syncthreads();

    // ctx = P @ V per head
    for (int p = lane; p < KREP * HD; p += 64) {
        int i = p >> 7, d = p & 127;
        float acc = 0.0f;
        for (int j = 0; j < KREP; ++j)
            acc += sat[h][i * KREP + j] * sv[h][j * APAD + d];
        ctx[(size_t)(b * KREP + i) * DV + h * HD + d] = acc;
    }
    // head-mean attention weights
    if (tid < KREP * KREP) {
        float s = 0.0f;
        for (int hh = 0; hh < NHEAD; ++hh) s += sat[hh][tid];
        out_attn[b * KREP * KREP + tid] = s * (1.0f / NHEAD);
    }
}

// ---------------- K8: refined = ctx @ out_w.T + out_b; 4 rows in regs per wave ----------------
__global__ void __launch_bounds__(256) k_proj(
        const float* __restrict__ ctx,
        const float* __restrict__ out_w, const float* __restrict__ out_b,
        float* __restrict__ refined) {
    int wid = threadIdx.x >> 6, lane = threadIdx.x & 63;
    int o0 = blockIdx.x * 4;
    const float4* w4 = (const float4*)out_w;
    float4 wr[4][4];
#pragma unroll
    for (int rr = 0; rr < 4; ++rr)
#pragma unroll
        for (int qq = 0; qq < 4; ++qq)
            wr[rr][qq] = w4[(size_t)(o0 + rr) * 256 + lane + 64 * qq];
#pragma unroll
    for (int tt = 0; tt < 12; ++tt) {
        int tok = wid + 4 * tt;
        const float4* f4 = (const float4*)(ctx + (size_t)tok * DV);
        float4 fq[4];
#pragma unroll
        for (int qq = 0; qq < 4; ++qq) fq[qq] = f4[lane + 64 * qq];
        float a0 = 0.f, a1 = 0.f, a2 = 0.f, a3 = 0.f;
#pragma unroll
        for (int qq = 0; qq < 4; ++qq) {
            float4 f = fq[qq];
            a0 += f.x * wr[0][qq].x + f.y * wr[0][qq].y + f.z * wr[0][qq].z + f.w * wr[0][qq].w;
            a1 += f.x * wr[1][qq].x + f.y * wr[1][qq].y + f.z * wr[1][qq].z + f.w * wr[1][qq].w;
            a2 += f.x * wr[2][qq].x + f.y * wr[2][qq].y + f.z * wr[2][qq].z + f.w * wr[2][qq].w;
            a3 += f.x * wr[3][qq].x + f.y * wr[3][qq].y + f.z * wr[3][qq].z + f.w * wr[3][qq].w;
        }
        a0 = wave_reduce_sumf(a0);
        a1 = wave_reduce_sumf(a1);
        a2 = wave_reduce_sumf(a2);
        a3 = wave_reduce_sumf(a3);
        if (lane == 0) {
            float* dst = refined + (size_t)tok * DV + o0;
            dst[0] = a0 + out_b[o0];
            dst[1] = a1 + out_b[o0 + 1];
            dst[2] = a2 + out_b[o0 + 2];
            dst[3] = a3 + out_b[o0 + 3];
        }
    }
}

// ---------------- launch ----------------
extern "C" void kernel_launch(void* const* d_in, const int* in_sizes, int n_in,
                              void* d_out, int out_size, void* d_ws, size_t ws_size,
                              hipStream_t stream) {
    const float* feat  = (const float*)d_in[0];
    const float* query = (const float*)d_in[1];
    const float* mu_w1 = (const float*)d_in[2];
    const float* mu_b1 = (const float*)d_in[3];
    const float* mu_g  = (const float*)d_in[4];
    const float* mu_bt = (const float*)d_in[5];
    const float* mu_w2 = (const float*)d_in[6];
    const float* mu_b2 = (const float*)d_in[7];
    const float* sg_w1 = (const float*)d_in[8];
    const float* sg_b1 = (const float*)d_in[9];
    const float* sg_g  = (const float*)d_in[10];
    const float* sg_bt = (const float*)d_in[11];
    const float* sg_w2 = (const float*)d_in[12];
    const float* sg_b2 = (const float*)d_in[13];
    const float* in_w  = (const float*)d_in[14];
    const float* in_b  = (const float*)d_in[15];
    const float* out_w = (const float*)d_in[16];
    const float* out_b = (const float*)d_in[17];

    float* out = (float*)d_out;
    float* out_refined = out;
    float* out_idx     = out + 49152;
    float* out_dist    = out + 49200;
    float* out_mu      = out + 114736;
    float* out_sg      = out + 122928;
    float* out_attn    = out + 131120;

    char* ws = (char*)d_ws;
    size_t off = 0;
    auto alloc = [&](size_t bytes) -> void* {
        void* p = (void*)(ws + off);
        off += (bytes + 255) & ~(size_t)255;
        return p;
    };
    double* h      = (double*)alloc((size_t)2 * BNUM * DV * sizeof(double));
    double* muw    = (double*)alloc((size_t)BNUM * DV * sizeof(double));
    double* rsig   = (double*)alloc((size_t)BNUM * DV * sizeof(double));
    double* distw  = (double*)alloc((size_t)BNUM * TNUM * sizeof(double));
    int*    idxi   = (int*)   alloc((size_t)BNUM * KREP * sizeof(int));
    float*  qkv    = (float*) alloc((size_t)BNUM * KREP * 3 * DV * sizeof(float));
    float*  ctx    = (float*) alloc((size_t)BNUM * KREP * DV * sizeof(float));

    k_mlp1<<<dim3(DV, BNUM, 2), 64, 0, stream>>>(query, mu_w1, mu_b1, sg_w1, sg_b1, h);
    k_ln  <<<dim3(BNUM, 2), 256, 0, stream>>>(h, mu_g, mu_bt, sg_g, sg_bt);
    k_mlp2<<<dim3(DV, BNUM, 2), 64, 0, stream>>>(h, mu_w2, mu_b2, sg_w2, sg_b2,
                                                 muw, rsig, out_mu, out_sg);
    k_dist<<<dim3(TNUM / 32, BNUM), 256, 0, stream>>>(feat, muw, rsig, distw, out_dist);
    k_select<<<dim3(BNUM), 1024, 0, stream>>>(distw, out_idx, idxi);
    k_qkv<<<dim3(3 * DV / 4), 256, 0, stream>>>(feat, idxi, in_w, in_b, qkv);
    k_attn<<<dim3(BNUM), 512, 0, stream>>>(qkv, ctx, out_attn);
    k_proj<<<dim3(DV / 4), 256, 0, stream>>>(ctx, out_w, out_b, out_refined);
}

// Round 5
// 499.149 us; speedup vs baseline: 1.0397x; 1.0397x over previous
//
#include <hip/hip_runtime.h>
#include <math.h>

#define TNUM 8192
#define BNUM 8
#define DV 1024
#define DQ 768
#define KREP 6
#define NHEAD 8
#define HD 128
#define CANDN 18
#define APAD 132   // LDS row stride for attn head tiles (132%32=4 -> no stride-128 bank conflict)

// ---------------- helpers ----------------
__device__ __forceinline__ double wave_reduce_sum(double v) {
    for (int off = 32; off > 0; off >>= 1) v += __shfl_down(v, off);
    return v;
}
__device__ __forceinline__ float wave_reduce_sumf(float v) {
    for (int off = 32; off > 0; off >>= 1) v += __shfl_down(v, off);
    return v;
}

// ---------------- K1: h = x @ w1.T + b1 (both branches, f64); x cached in regs ----------------
__global__ void __launch_bounds__(64) k_mlp1(
        const float* __restrict__ q,
        const float* __restrict__ mu_w1, const float* __restrict__ mu_b1,
        const float* __restrict__ sg_w1, const float* __restrict__ sg_b1,
        double* __restrict__ h) {
    int o0 = blockIdx.x * 4, b = blockIdx.y, br = blockIdx.z;
    const float* w  = br ? sg_w1 : mu_w1;
    const float* bb = br ? sg_b1 : mu_b1;
    const float* x  = q + (size_t)b * DQ;
    int lane = threadIdx.x;
    double xv[12];
#pragma unroll
    for (int k = 0; k < 12; ++k) xv[k] = (double)x[lane + 64 * k];
#pragma unroll
    for (int oo = 0; oo < 4; ++oo) {
        int o = o0 + oo;
        const float* wr = w + (size_t)o * DQ;
        double acc = 0.0;
#pragma unroll
        for (int k = 0; k < 12; ++k)
            acc += xv[k] * (double)wr[lane + 64 * k];
        acc = wave_reduce_sum(acc);
        if (lane == 0)
            h[((size_t)br * BNUM + b) * DV + o] = acc + (double)bb[o];
    }
}

// ---------------- K2: fused LN+ReLU+mlp2; h-row cached in regs, stats recomputed per block ----------------
__global__ void __launch_bounds__(64) k_mlp2ln(
        const double* __restrict__ h,
        const float* __restrict__ mu_w2, const float* __restrict__ mu_b2,
        const float* __restrict__ mu_g,  const float* __restrict__ mu_bt,
        const float* __restrict__ sg_w2, const float* __restrict__ sg_b2,
        const float* __restrict__ sg_g,  const float* __restrict__ sg_bt,
        double* __restrict__ mu, double* __restrict__ rsig,
        float* __restrict__ out_mu, float* __restrict__ out_sg) {
    int o0 = blockIdx.x * 4, b = blockIdx.y, br = blockIdx.z;
    const float* w  = br ? sg_w2 : mu_w2;
    const float* bb = br ? sg_b2 : mu_b2;
    const float* g  = br ? sg_g  : mu_g;
    const float* bt = br ? sg_bt : mu_bt;
    const double* row = h + ((size_t)br * BNUM + b) * DV;
    int lane = threadIdx.x;

    double rv[16];
#pragma unroll
    for (int k = 0; k < 16; ++k) rv[k] = row[lane + 64 * k];

    double s = 0.0;
#pragma unroll
    for (int k = 0; k < 16; ++k) s += rv[k];
    s = wave_reduce_sum(s);
    double mean = __shfl(s, 0) / (double)DV;

    double v = 0.0;
#pragma unroll
    for (int k = 0; k < 16; ++k) { double c = rv[k] - mean; v += c * c; }
    v = wave_reduce_sum(v);
    double rstd = 1.0 / sqrt(__shfl(v, 0) / (double)DV + 1e-5);

    double hn[16];
#pragma unroll
    for (int k = 0; k < 16; ++k) {
        double val = (rv[k] - mean) * rstd * (double)g[lane + 64 * k] + (double)bt[lane + 64 * k];
        hn[k] = val > 0.0 ? val : 0.0;
    }

#pragma unroll
    for (int oo = 0; oo < 4; ++oo) {
        int o = o0 + oo;
        const float* wr = w + (size_t)o * DV;
        double acc = 0.0;
#pragma unroll
        for (int k = 0; k < 16; ++k)
            acc += hn[k] * (double)wr[lane + 64 * k];
        acc = wave_reduce_sum(acc);
        if (lane == 0) {
            double vo = acc + (double)bb[o];
            if (br == 0) {
                mu[(size_t)b * DV + o] = vo;
                out_mu[b * DV + o] = (float)vo;
            } else {
                double sp = fmax(vo, 0.0) + log1p(exp(-fabs(vo)));  // stable softplus
                double sig = sp + 1e-6;
                rsig[(size_t)b * DV + o] = 1.0 / sig;
                out_sg[b * DV + o] = (float)sig;
            }
        }
    }
}

// ---------------- K3: Mahalanobis dist; mu/rsig cached in registers, 32 rows/block ----------------
__global__ void __launch_bounds__(256) k_dist(
        const float* __restrict__ feat,
        const double* __restrict__ mu, const double* __restrict__ rsig,
        double* __restrict__ distw, float* __restrict__ dist_out) {
    int wid = threadIdx.x >> 6, lane = threadIdx.x & 63;
    int b = blockIdx.y;
    int t0 = blockIdx.x * 32;
    const double* m = mu   + (size_t)b * DV;
    const double* r = rsig + (size_t)b * DV;
    double md[4][4], rd[4][4];
#pragma unroll
    for (int qq = 0; qq < 4; ++qq) {
        int j = (lane + 64 * qq) * 4;
#pragma unroll
        for (int e = 0; e < 4; ++e) { md[qq][e] = m[j + e]; rd[qq][e] = r[j + e]; }
    }
#pragma unroll 2
    for (int rr = 0; rr < 8; ++rr) {
        int t = t0 + rr * 4 + wid;
        const float4* f4 = (const float4*)(feat + ((size_t)b * TNUM + t) * DV);
        double acc = 0.0;
#pragma unroll
        for (int qq = 0; qq < 4; ++qq) {
            float4 f = f4[lane + 64 * qq];
            double c0 = (double)f.x - md[qq][0];
            double c1 = (double)f.y - md[qq][1];
            double c2 = (double)f.z - md[qq][2];
            double c3 = (double)f.w - md[qq][3];
            acc += c0 * c0 * rd[qq][0] + c1 * c1 * rd[qq][1]
                 + c2 * c2 * rd[qq][2] + c3 * c3 * rd[qq][3];
        }
        acc = wave_reduce_sum(acc);
        if (lane == 0) {
            distw[(size_t)b * TNUM + t] = acc;
            dist_out[b * TNUM + t] = (float)acc;
        }
    }
}

// ---------------- K4: radix-select (normalized keys) + top-18 + diversify ----------------
struct SelShared {
    unsigned int hist[256];
    unsigned long long pref;
    int krem;
    unsigned long long kmn[16], kmx[16];
    unsigned long long s_kmin;
    int s_shift;
};

__device__ __forceinline__ unsigned long long raw_key(double v) {
    return (unsigned long long)__double_as_longlong(v);
}

__device__ void block_norm_params(const double* sw, int absmode, double med,
                                  SelShared* S, int tid) {
    unsigned long long mn = ~0ULL, mx = 0ULL;
    for (int i = tid; i < TNUM; i += 1024) {
        double v = sw[i];
        if (absmode) v = fabs(v - med);
        unsigned long long k = raw_key(v);
        mn = mn < k ? mn : k;
        mx = mx > k ? mx : k;
    }
    for (int off = 32; off > 0; off >>= 1) {
        unsigned long long omn = __shfl_down(mn, off);
        unsigned long long omx = __shfl_down(mx, off);
        mn = mn < omn ? mn : omn;
        mx = mx > omx ? mx : omx;
    }
    int lane = tid & 63, wid = tid >> 6;
    if (lane == 0) { S->kmn[wid] = mn; S->kmx[wid] = mx; }
    __syncthreads();
    if (tid == 0) {
        unsigned long long fmn = S->kmn[0], fmx = S->kmx[0];
        for (int k = 1; k < 16; ++k) {
            if (S->kmn[k] < fmn) fmn = S->kmn[k];
            if (S->kmx[k] > fmx) fmx = S->kmx[k];
        }
        unsigned long long diff = fmx - fmn;
        S->s_kmin = fmn;
        S->s_shift = diff ? __clzll((long long)diff) : 0;
    }
    __syncthreads();
}

__device__ __forceinline__ unsigned long long norm_key(double v, int absmode, double med,
                                                       unsigned long long kmin, int shift) {
    unsigned long long k = raw_key(absmode ? fabs(v - med) : v);
    return (k - kmin) << shift;
}

__device__ unsigned long long block_radix_select(
        const double* sw, int rank, int absmode, double med, SelShared* S, int tid) {
    unsigned long long kmin = S->s_kmin;
    int shift = S->s_shift;
    if (tid == 0) { S->pref = 0ULL; S->krem = rank; }
    __syncthreads();
    for (int p = 0; p < 8; ++p) {
        for (int cc = tid; cc < 256; cc += 1024) S->hist[cc] = 0;
        __syncthreads();
        unsigned long long pref = S->pref;
        int known = 8 * p;
        int sh = 56 - known;
        for (int i = tid; i < TNUM; i += 1024) {
            unsigned long long key = norm_key(sw[i], absmode, med, kmin, shift);
            bool ok = (known == 0) || ((key >> (64 - known)) == (pref >> (64 - known)));
            if (ok) atomicAdd(&S->hist[(unsigned)((key >> sh) & 255ULL)], 1u);
        }
        __syncthreads();
        if (tid < 64) {
            unsigned int s0 = S->hist[tid * 4] + S->hist[tid * 4 + 1] +
                              S->hist[tid * 4 + 2] + S->hist[tid * 4 + 3];
            unsigned int incl = s0;
            for (int off = 1; off < 64; off <<= 1) {
                unsigned int v = __shfl_up(incl, off);
                if (tid >= off) incl += v;
            }
            int krem = S->krem;
            unsigned long long msk = __ballot(incl > (unsigned int)krem);
            int fl = __ffsll((unsigned long long)msk) - 1;
            if (tid == fl) {
                int k = krem - (int)(incl - s0);
                int c = tid * 4;
                while (k >= (int)S->hist[c]) { k -= (int)S->hist[c]; ++c; }
                S->krem = k;
                S->pref = pref | ((unsigned long long)(unsigned)c << sh);
            }
        }
        __syncthreads();
    }
    return S->pref;
}

__global__ void __launch_bounds__(1024) k_select(
        const double* __restrict__ distw,
        float* __restrict__ idx_out, int* __restrict__ idx_int) {
    __shared__ double sw[TNUM];           // 64 KB
    __shared__ SelShared S;
    __shared__ int s_cntlt, s_cnteq, s_nlt;
    __shared__ int s_lt[32];
    __shared__ int s_eq[64];
    __shared__ int s_eqs[CANDN];
    __shared__ int s_cand[CANDN];
    int b = blockIdx.x, tid = threadIdx.x;
    const double* w = distw + (size_t)b * TNUM;
    for (int i = tid; i < TNUM; i += 1024) sw[i] = w[i];
    __syncthreads();

    // lower median: rank 4095 of 8192
    block_norm_params(sw, 0, 0.0, &S, tid);
    unsigned long long kmin1 = S.s_kmin; int shift1 = S.s_shift;
    unsigned long long mk = block_radix_select(sw, (TNUM - 1) / 2, 0, 0.0, &S, tid);
    double med = __longlong_as_double((long long)((mk >> shift1) + kmin1));
    __syncthreads();

    // 18th-smallest |d - med| (normalized key K)
    block_norm_params(sw, 1, med, &S, tid);
    unsigned long long kmin2 = S.s_kmin; int shift2 = S.s_shift;
    unsigned long long K = block_radix_select(sw, CANDN - 1, 1, med, &S, tid);

    if (tid == 0) { s_cntlt = 0; s_cnteq = 0; }
    __syncthreads();
    for (int i = tid; i < TNUM; i += 1024) {
        unsigned long long key = norm_key(sw[i], 1, med, kmin2, shift2);
        if (key < K) { int p = atomicAdd(&s_cntlt, 1); if (p < 32) s_lt[p] = i; }
        else if (key == K) { int p = atomicAdd(&s_cnteq, 1); if (p < 64) s_eq[p] = i; }
    }
    __syncthreads();

    // wave 0: sort eq-class by index, keep the (18 - nlt) smallest
    if (tid < 64) {
        int nlt = s_cntlt; if (nlt > CANDN - 1) nlt = CANDN - 1;
        int neq = s_cnteq; if (neq > 64) neq = 64;
        int need = CANDN - nlt;
        int mye = (tid < neq) ? s_eq[tid] : 0x7FFFFFFF;
        int r = 0;
        for (int j = 0; j < neq; ++j) { int oj = __shfl(mye, j); if (oj < mye) ++r; }
        if (tid < neq && r < need) s_eqs[r] = mye;
        if (tid == 0) s_nlt = nlt;
    }
    __syncthreads();

    // wave 0: rank-sort the 18 candidates by (key, idx) ascending = lax.top_k order
    if (tid < 64) {
        int nlt = s_nlt;
        unsigned long long mykey; int myidx;
        if (tid < nlt) {
            myidx = s_lt[tid];
            mykey = norm_key(sw[myidx], 1, med, kmin2, shift2);
        } else if (tid < CANDN) {
            myidx = s_eqs[tid - nlt];
            mykey = K;
        } else { myidx = 0x7FFFFFFF; mykey = ~0ULL; }
        int r = 0;
        for (int j = 0; j < CANDN; ++j) {
            unsigned long long kj = __shfl(mykey, j);
            int ij = __shfl(myidx, j);
            if (kj < mykey || (kj == mykey && ij < myidx)) ++r;
        }
        if (tid < CANDN) s_cand[r] = myidx;
    }
    __syncthreads();

    // wave 0: greedy farthest-point diversify (f32, argmax first-occurrence)
    if (tid < 64) {
        int ci = (tid < CANDN) ? s_cand[tid] : 0;
        float cf = (float)ci;
        float c0 = __shfl(cf, 0);
        const float NEG = -__builtin_huge_valf();
        float mind = (tid < CANDN) ? fabsf(cf - c0) : NEG;
        if (tid == 0) {
            mind = NEG;
            idx_out[b * KREP] = (float)ci;
            idx_int[b * KREP] = ci;
        }
        for (int s = 1; s < KREP; ++s) {
            float bv = mind; int bl = tid;
            for (int off = 32; off > 0; off >>= 1) {
                float ov = __shfl_down(bv, off);
                int   ol = __shfl_down(bl, off);
                if (ov > bv || (ov == bv && ol < bl)) { bv = ov; bl = ol; }
            }
            int bestlane = __shfl(bl, 0);
            float bf = __shfl(cf, bestlane);
            int   bi = __shfl(ci, bestlane);
            if (tid == 0) {
                idx_out[b * KREP + s] = (float)bi;
                idx_int[b * KREP + s] = bi;
            }
            mind = fminf(mind, fabsf(cf - bf));
            if (tid == bestlane) mind = NEG;
        }
    }
}

// ---------------- K5: qkv = rep @ in_w.T + in_b; 4 weight rows in regs per wave ----------------
__global__ void __launch_bounds__(256) k_qkv(
        const float* __restrict__ feat, const int* __restrict__ idxi,
        const float* __restrict__ in_w, const float* __restrict__ in_b,
        float* __restrict__ qkv) {
    int wid = threadIdx.x >> 6, lane = threadIdx.x & 63;
    int o0 = blockIdx.x * 4;
    const float4* w4 = (const float4*)in_w;
    float4 wr[4][4];
#pragma unroll
    for (int rr = 0; rr < 4; ++rr)
#pragma unroll
        for (int qq = 0; qq < 4; ++qq)
            wr[rr][qq] = w4[(size_t)(o0 + rr) * 256 + lane + 64 * qq];
#pragma unroll
    for (int tt = 0; tt < 12; ++tt) {
        int tok = wid + 4 * tt;
        int b = tok / KREP;
        int t = idxi[tok];
        const float4* f4 = (const float4*)(feat + ((size_t)b * TNUM + t) * DV);
        float4 fq[4];
#pragma unroll
        for (int qq = 0; qq < 4; ++qq) fq[qq] = f4[lane + 64 * qq];
        float a0 = 0.f, a1 = 0.f, a2 = 0.f, a3 = 0.f;
#pragma unroll
        for (int qq = 0; qq < 4; ++qq) {
            float4 f = fq[qq];
            a0 += f.x * wr[0][qq].x + f.y * wr[0][qq].y + f.z * wr[0][qq].z + f.w * wr[0][qq].w;
            a1 += f.x * wr[1][qq].x + f.y * wr[1][qq].y + f.z * wr[1][qq].z + f.w * wr[1][qq].w;
            a2 += f.x * wr[2][qq].x + f.y * wr[2][qq].y + f.z * wr[2][qq].z + f.w * wr[2][qq].w;
            a3 += f.x * wr[3][qq].x + f.y * wr[3][qq].y + f.z * wr[3][qq].z + f.w * wr[3][qq].w;
        }
        a0 = wave_reduce_sumf(a0);
        a1 = wave_reduce_sumf(a1);
        a2 = wave_reduce_sumf(a2);
        a3 = wave_reduce_sumf(a3);
        if (lane == 0) {
            float* dst = qkv + (size_t)tok * (3 * DV) + o0;
            dst[0] = a0 + in_b[o0];
            dst[1] = a1 + in_b[o0 + 1];
            dst[2] = a2 + in_b[o0 + 2];
            dst[3] = a3 + in_b[o0 + 3];
        }
    }
}

// ---------------- K6: fused attention + head-mean; one block per batch, one wave per head ----------------
__global__ void __launch_bounds__(512) k_attn(
        const float* __restrict__ qkv,
        float* __restrict__ ctx, float* __restrict__ out_attn) {
    int b = blockIdx.x;
    int tid = threadIdx.x, h = tid >> 6, lane = tid & 63;
    __shared__ float sq[NHEAD][KREP * APAD];
    __shared__ float sk[NHEAD][KREP * APAD];
    __shared__ float sv[NHEAD][KREP * APAD];
    __shared__ float sat[NHEAD][KREP * KREP];

    for (int p = lane; p < KREP * HD; p += 64) {
        int i = p >> 7, d = p & 127;
        size_t base = (size_t)(b * KREP + i) * (3 * DV) + h * HD + d;
        sq[h][i * APAD + d] = qkv[base];
        sk[h][i * APAD + d] = qkv[base + DV];
        sv[h][i * APAD + d] = qkv[base + 2 * DV];
    }
    __syncthreads();

    if (lane < KREP * KREP) {
        int i = lane / KREP, j = lane % KREP;
        float s = 0.0f;
        for (int d = 0; d < HD; ++d)
            s += sq[h][i * APAD + d] * sk[h][j * APAD + d];
        sat[h][lane] = s / sqrtf((float)HD);
    }
    __syncthreads();

    if (lane < KREP) {
        int i = lane;
        float m = sat[h][i * KREP];
        for (int j = 1; j < KREP; ++j) m = fmaxf(m, sat[h][i * KREP + j]);
        float sum = 0.0f;
        for (int j = 0; j < KREP; ++j) {
            float e = expf(sat[h][i * KREP + j] - m);
            sum += e; sat[h][i * KREP + j] = e;
        }
        float inv = 1.0f / sum;
        for (int j = 0; j < KREP; ++j) sat[h][i * KREP + j] *= inv;
    }
    __syncthreads();

    // ctx = P @ V per head
    for (int p = lane; p < KREP * HD; p += 64) {
        int i = p >> 7, d = p & 127;
        float acc = 0.0f;
        for (int j = 0; j < KREP; ++j)
            acc += sat[h][i * KREP + j] * sv[h][j * APAD + d];
        ctx[(size_t)(b * KREP + i) * DV + h * HD + d] = acc;
    }
    // head-mean attention weights
    if (tid < KREP * KREP) {
        float s = 0.0f;
        for (int hh = 0; hh < NHEAD; ++hh) s += sat[hh][tid];
        out_attn[b * KREP * KREP + tid] = s * (1.0f / NHEAD);
    }
}

// ---------------- K7: refined = ctx @ out_w.T + out_b; 4 rows in regs per wave ----------------
__global__ void __launch_bounds__(256) k_proj(
        const float* __restrict__ ctx,
        const float* __restrict__ out_w, const float* __restrict__ out_b,
        float* __restrict__ refined) {
    int wid = threadIdx.x >> 6, lane = threadIdx.x & 63;
    int o0 = blockIdx.x * 4;
    const float4* w4 = (const float4*)out_w;
    float4 wr[4][4];
#pragma unroll
    for (int rr = 0; rr < 4; ++rr)
#pragma unroll
        for (int qq = 0; qq < 4; ++qq)
            wr[rr][qq] = w4[(size_t)(o0 + rr) * 256 + lane + 64 * qq];
#pragma unroll
    for (int tt = 0; tt < 12; ++tt) {
        int tok = wid + 4 * tt;
        const float4* f4 = (const float4*)(ctx + (size_t)tok * DV);
        float4 fq[4];
#pragma unroll
        for (int qq = 0; qq < 4; ++qq) fq[qq] = f4[lane + 64 * qq];
        float a0 = 0.f, a1 = 0.f, a2 = 0.f, a3 = 0.f;
#pragma unroll
        for (int qq = 0; qq < 4; ++qq) {
            float4 f = fq[qq];
            a0 += f.x * wr[0][qq].x + f.y * wr[0][qq].y + f.z * wr[0][qq].z + f.w * wr[0][qq].w;
            a1 += f.x * wr[1][qq].x + f.y * wr[1][qq].y + f.z * wr[1][qq].z + f.w * wr[1][qq].w;
            a2 += f.x * wr[2][qq].x + f.y * wr[2][qq].y + f.z * wr[2][qq].z + f.w * wr[2][qq].w;
            a3 += f.x * wr[3][qq].x + f.y * wr[3][qq].y + f.z * wr[3][qq].z + f.w * wr[3][qq].w;
        }
        a0 = wave_reduce_sumf(a0);
        a1 = wave_reduce_sumf(a1);
        a2 = wave_reduce_sumf(a2);
        a3 = wave_reduce_sumf(a3);
        if (lane == 0) {
            float* dst = refined + (size_t)tok * DV + o0;
            dst[0] = a0 + out_b[o0];
            dst[1] = a1 + out_b[o0 + 1];
            dst[2] = a2 + out_b[o0 + 2];
            dst[3] = a3 + out_b[o0 + 3];
        }
    }
}

// ---------------- launch ----------------
extern "C" void kernel_launch(void* const* d_in, const int* in_sizes, int n_in,
                              void* d_out, int out_size, void* d_ws, size_t ws_size,
                              hipStream_t stream) {
    const float* feat  = (const float*)d_in[0];
    const float* query = (const float*)d_in[1];
    const float* mu_w1 = (const float*)d_in[2];
    const float* mu_b1 = (const float*)d_in[3];
    const float* mu_g  = (const float*)d_in[4];
    const float* mu_bt = (const float*)d_in[5];
    const float* mu_w2 = (const float*)d_in[6];
    const float* mu_b2 = (const float*)d_in[7];
    const float* sg_w1 = (const float*)d_in[8];
    const float* sg_b1 = (const float*)d_in[9];
    const float* sg_g  = (const float*)d_in[10];
    const float* sg_bt = (const float*)d_in[11];
    const float* sg_w2 = (const float*)d_in[12];
    const float* sg_b2 = (const float*)d_in[13];
    const float* in_w  = (const float*)d_in[14];
    const float* in_b  = (const float*)d_in[15];
    const float* out_w = (const float*)d_in[16];
    const float* out_b = (const float*)d_in[17];

    float* out = (float*)d_out;
    float* out_refined = out;
    float* out_idx     = out + 49152;
    float* out_dist    = out + 49200;
    float* out_mu      = out + 114736;
    float* out_sg      = out + 122928;
    float* out_attn    = out + 131120;

    char* ws = (char*)d_ws;
    size_t off = 0;
    auto alloc = [&](size_t bytes) -> void* {
        void* p = (void*)(ws + off);
        off += (bytes + 255) & ~(size_t)255;
        return p;
    };
    double* h      = (double*)alloc((size_t)2 * BNUM * DV * sizeof(double));
    double* muw    = (double*)alloc((size_t)BNUM * DV * sizeof(double));
    double* rsig   = (double*)alloc((size_t)BNUM * DV * sizeof(double));
    double* distw  = (double*)alloc((size_t)BNUM * TNUM * sizeof(double));
    int*    idxi   = (int*)   alloc((size_t)BNUM * KREP * sizeof(int));
    float*  qkv    = (float*) alloc((size_t)BNUM * KREP * 3 * DV * sizeof(float));
    float*  ctx    = (float*) alloc((size_t)BNUM * KREP * DV * sizeof(float));

    k_mlp1<<<dim3(DV / 4, BNUM, 2), 64, 0, stream>>>(query, mu_w1, mu_b1, sg_w1, sg_b1, h);
    k_mlp2ln<<<dim3(DV / 4, BNUM, 2), 64, 0, stream>>>(h, mu_w2, mu_b2, mu_g, mu_bt,
                                                       sg_w2, sg_b2, sg_g, sg_bt,
                                                       muw, rsig, out_mu, out_sg);
    k_dist<<<dim3(TNUM / 32, BNUM), 256, 0, stream>>>(feat, muw, rsig, distw, out_dist);
    k_select<<<dim3(BNUM), 1024, 0, stream>>>(distw, out_idx, idxi);
    k_qkv<<<dim3(3 * DV / 4), 256, 0, stream>>>(feat, idxi, in_w, in_b, qkv);
    k_attn<<<dim3(BNUM), 512, 0, stream>>>(qkv, ctx, out_attn);
    k_proj<<<dim3(DV / 4), 256, 0, stream>>>(ctx, out_w, out_b, out_refined);
}